// Round 4
// baseline (212.573 us; speedup 1.0000x reference)
//
#include <hip/hip_runtime.h>

// SGConv: K=3 hops of \hat{A} x (symmetric gcn_norm w/ self-loops), then Linear.
// N=100000, E=1600000, F_in=32, F_out=64.
// Round 20: temporal phase-split of each hop into L2-sized source halves.
// Model from R17/R18/R19: hop time moves ONLY with line-touch count ->
// shared-cache (L3) line-service-rate bound; 6.4MB state > 4MB/XCD L2 means
// ~60% of gather touches are L3-serviced. Fix WITHOUT adding touches:
// fill3 orders each node's col segment [src<N/2 | src>=N/2] (two-cursor
// counting sort, split point in nrec.w); hop kernels run lo-phase then
// hi-phase loops with a block barrier between. All hop blocks co-resident
// -> device-wide soft lockstep -> active gather set 3.2MB fits per-XCD L2.
// Accumulators stay in registers (no partial round-trip - R18's mistake).
// nt hints ONLY on streams (col/nrec/gout) to protect residency.
// Keep (R17 best, 200.3us): two-level radix build, per-wave replicated bin
// counters, fill3+prescale fusion, 4 lanes/node 16B gathers, unroll-4,
// fused hop3+linear conflict-free epilogue.

#define F_IN 32
#define F_OUT 64
#define SB_SHIFT 13                  // 8192 nodes per super-bucket
#define NSB_MAX 16
#define SUB_SHIFT 8                  // 256 nodes per sub-bucket
#define SUB (1 << SUB_SHIFT)
#define SPS 32                       // subs per super (8192/256)
#define EPB1 2048
#define EPB2 4096
#define SCAP 147456                  // super slab cap (mean 131072, sd ~347)
#define SUBCAP 6144                  // sub slab cap (mean 4096, sd ~64)
#define BPS (SCAP / EPB2)            // 36 blocks per super in k_bin2

typedef float f4 __attribute__((ext_vector_type(4)));
typedef float f8 __attribute__((ext_vector_type(8)));
typedef _Float16 h8 __attribute__((ext_vector_type(8)));   // 16B
typedef int i4 __attribute__((ext_vector_type(4)));

// ---------- Level-1 bin: 13 supers; per-wave replicated hist/cursors ----------
__global__ __launch_bounds__(256) void k_bin1(const int* __restrict__ ei,
                                              int* __restrict__ scur,
                                              unsigned* __restrict__ b1, int E) {
    __shared__ unsigned stage[EPB1];          // 8 KB
    __shared__ unsigned char bidl[EPB1];      // 2 KB
    __shared__ int h4w[4][NSB_MAX];           // per-wave hist
    __shared__ int f4w[4][NSB_MAX];           // per-wave cursors
    __shared__ int lscanx[NSB_MAX], lbase[NSB_MAX];
    unsigned rec[EPB1 / 256];
    int      bk[EPB1 / 256];
    int tid = threadIdx.x;
    int wv = tid >> 6;
    int base = blockIdx.x * EPB1;
    int cnt = E - base; if (cnt > EPB1) cnt = EPB1;

    if (tid < 64) { h4w[tid >> 4][tid & 15] = 0; }
    __syncthreads();
#pragma unroll
    for (int k = 0; k < EPB1 / 256; ++k) {
        int i = base + k * 256 + tid;
        bk[k] = -1;
        if (i < E) {
            unsigned s = (unsigned)ei[i];
            unsigned d = (unsigned)ei[E + i];
            int b = d >> SB_SHIFT;
            rec[k] = (s << SB_SHIFT) | (d & ((1u << SB_SHIFT) - 1));
            bk[k] = b;
            atomicAdd(&h4w[wv][b], 1);
        }
    }
    __syncthreads();
    if (tid < 16) {
        int t0 = h4w[0][tid], t1 = h4w[1][tid], t2 = h4w[2][tid], t3 = h4w[3][tid];
        int tot = t0 + t1 + t2 + t3;
        int inc = tot;
#pragma unroll
        for (int off = 1; off < 16; off <<= 1) {
            int t = __shfl_up(inc, off);
            if (tid >= off) inc += t;
        }
        int excl = inc - tot;
        lscanx[tid] = excl;
        lbase[tid] = tot ? atomicAdd(&scur[tid], tot) : 0;
        f4w[0][tid] = excl;
        f4w[1][tid] = excl + t0;
        f4w[2][tid] = excl + t0 + t1;
        f4w[3][tid] = excl + t0 + t1 + t2;
    }
    __syncthreads();
#pragma unroll
    for (int k = 0; k < EPB1 / 256; ++k) {
        if (bk[k] >= 0) {
            int loc = atomicAdd(&f4w[wv][bk[k]], 1);
            stage[loc] = rec[k];
            bidl[loc] = (unsigned char)bk[k];
        }
    }
    __syncthreads();
    for (int k = 0; k < EPB1 / 256; ++k) {
        int idx = k * 256 + tid;
        if (idx < cnt) {
            int b = bidl[idx];
            b1[(size_t)b * SCAP + lbase[b] + (idx - lscanx[b])] = stage[idx];
        }
    }
}

// ---------- Level-2 bin: 32 subs per super; per-wave replicated ----------
__global__ __launch_bounds__(256) void k_bin2(const unsigned* __restrict__ b1,
                                              const int* __restrict__ scur,
                                              int* __restrict__ subcur,
                                              unsigned* __restrict__ b2) {
    int sb = blockIdx.x / BPS;
    int base = (blockIdx.x % BPS) * EPB2;
    int count = scur[sb];
    if (base >= count) return;
    int cnt = count - base; if (cnt > EPB2) cnt = EPB2;
    const unsigned* src = b1 + (size_t)sb * SCAP + base;

    __shared__ unsigned stage[EPB2];          // 16 KB
    __shared__ unsigned char bidl[EPB2];      // 4 KB
    __shared__ int h4w[4][SPS];
    __shared__ int f4w[4][SPS];
    __shared__ int lscanx[SPS], lbase[SPS];
    unsigned rec[EPB2 / 256];
    int tid = threadIdx.x;
    int wv = tid >> 6;
    if (tid < 128) h4w[tid >> 5][tid & 31] = 0;
    __syncthreads();
#pragma unroll
    for (int k = 0; k < EPB2 / 256; ++k) {
        int i = k * 256 + tid;
        rec[k] = 0xFFFFFFFFu;
        if (i < cnt) {
            unsigned r = src[i];
            rec[k] = r;
            atomicAdd(&h4w[wv][(r >> SUB_SHIFT) & (SPS - 1)], 1);
        }
    }
    __syncthreads();
    if (tid < 32) {
        int t0 = h4w[0][tid], t1 = h4w[1][tid], t2 = h4w[2][tid], t3 = h4w[3][tid];
        int tot = t0 + t1 + t2 + t3;
        int inc = tot;
#pragma unroll
        for (int off = 1; off < 32; off <<= 1) {
            int t = __shfl_up(inc, off);
            if (tid >= off) inc += t;
        }
        int excl = inc - tot;
        lscanx[tid] = excl;
        lbase[tid] = tot ? atomicAdd(&subcur[sb * SPS + tid], tot) : 0;
        f4w[0][tid] = excl;
        f4w[1][tid] = excl + t0;
        f4w[2][tid] = excl + t0 + t1;
        f4w[3][tid] = excl + t0 + t1 + t2;
    }
    __syncthreads();
#pragma unroll
    for (int k = 0; k < EPB2 / 256; ++k) {
        if (rec[k] != 0xFFFFFFFFu) {
            int b = (rec[k] >> SUB_SHIFT) & (SPS - 1);
            int loc = atomicAdd(&f4w[wv][b], 1);
            stage[loc] = rec[k];
            bidl[loc] = (unsigned char)b;
        }
    }
    __syncthreads();
    for (int k = 0; k < EPB2 / 256; ++k) {
        int idx = k * 256 + tid;
        if (idx < cnt) {
            unsigned r = stage[idx];
            int b = bidl[idx];
            unsigned packed = ((r >> SB_SHIFT) << SUB_SHIFT) | (r & (SUB - 1));
            b2[(size_t)(sb * SPS + b) * SUBCAP + lbase[b] + (idx - lscanx[b])] = packed;
        }
    }
}

// ---------- fill3: two-cursor counting sort (lo|hi src halves per node);
// ---------- packed nrec (e0,e1,dinv,esplit); fused prescale ----------
__global__ __launch_bounds__(256) void k_fill3(const unsigned* __restrict__ b2,
                                               const int* __restrict__ subcur,
                                               const f4* __restrict__ x,
                                               i4* __restrict__ nrec,
                                               int* __restrict__ col,
                                               h8* __restrict__ g0, int N, int Nhalf) {
    __shared__ unsigned stage[SUBCAP];        // 24 KB
    __shared__ int h[SUB];                    // total counts -> lo cursor
    __shared__ int hlo[SUB];                  // lo counts -> hi cursor
    __shared__ float dl[SUB];
    __shared__ int wsum[4];
    int tid = threadIdx.x;
    int g = blockIdx.x;
    int count = subcur[g];
    int sbase = g * SUBCAP;
    int n0 = g << SUB_SHIFT;

    h[tid] = 0;
    hlo[tid] = 0;
    for (int e = tid; e < count; e += 256) stage[e] = b2[(size_t)sbase + e];
    __syncthreads();
    for (int e = tid; e < count; e += 256) {
        unsigned r = stage[e];
        int nd = r & (SUB - 1);
        atomicAdd(&h[nd], 1);
        if ((int)(r >> SUB_SHIFT) < Nhalf) atomicAdd(&hlo[nd], 1);
    }
    __syncthreads();

    int deg = h[tid];
    int dlo = hlo[tid];
    int lane = tid & 63, wid = tid >> 6;
    int inc = deg;
#pragma unroll
    for (int off = 1; off < 64; off <<= 1) {
        int t = __shfl_up(inc, off);
        if (lane >= off) inc += t;
    }
    if (lane == 63) wsum[wid] = inc;
    __syncthreads();
    if (wid == 0) {
        int v = (lane < 4) ? wsum[lane] : 0;
#pragma unroll
        for (int off = 1; off < 4; off <<= 1) {
            int t = __shfl_up(v, off);
            if (lane >= off) v += t;
        }
        if (lane < 4) wsum[lane] = v;
    }
    __syncthreads();
    int incl = inc + (wid ? wsum[wid - 1] : 0);
    int excl = incl - deg;

    int node = n0 + tid;
    float di = rsqrtf(1.0f + (float)deg);
    dl[tid] = di;
    if (node < N) {
        int e0a = sbase + excl;
        nrec[node] = (i4){e0a, e0a + deg, (int)__float_as_int(di), e0a + dlo};
    }
    h[tid] = excl;           // lo cursor
    hlo[tid] = excl + dlo;   // hi cursor
    __syncthreads();

    for (int e = tid; e < count; e += 256) {
        unsigned r = stage[e];
        int nd = r & (SUB - 1);
        int src = (int)(r >> SUB_SHIFT);
        int slot = (src < Nhalf) ? atomicAdd(&h[nd], 1) : atomicAdd(&hlo[nd], 1);
        col[sbase + slot] = src;
    }

    // fused prescale: g0 = fp16(dinv .* x), full 64B rows
    for (int idx = tid; idx < SUB * 4; idx += 256) {
        int nl = idx >> 2;
        int q = idx & 3;
        int node2 = n0 + nl;
        if (node2 < N) {
            int gi = node2 * 8 + q * 2;
            f4 vlo = dl[nl] * x[gi];
            f4 vhi = dl[nl] * x[gi + 1];
            f8 v = __builtin_shufflevector(vlo, vhi, 0, 1, 2, 3, 4, 5, 6, 7);
            g0[(size_t)node2 * 4 + q] = __builtin_convertvector(v, h8);
        }
    }
}

// ---------- Mid hop (hops 1,2): 4 lanes/row, 16B gathers, TWO PHASES:
// ---------- lo-half sources, barrier, hi-half sources ----------
__global__ __launch_bounds__(256) void k_hop_gather(const i4* __restrict__ nrec,
                                                    const int* __restrict__ col,
                                                    const h8* __restrict__ gin,
                                                    h8* __restrict__ gout, int N) {
    int t = blockIdx.x * blockDim.x + threadIdx.x;
    int n = t >> 2;
    int q = t & 3;
    bool act = n < N;
    int e0 = 0, e1 = 0, es = 0;
    float di = 0.f;
    f8 a0 = {0.f, 0.f, 0.f, 0.f, 0.f, 0.f, 0.f, 0.f};
    f8 a1 = {0.f, 0.f, 0.f, 0.f, 0.f, 0.f, 0.f, 0.f};
    if (act) {
        i4 r = __builtin_nontemporal_load(&nrec[n]);
        e0 = r.x; e1 = r.y; es = r.w;
        di = __int_as_float(r.z);
        a0 = __builtin_convertvector(gin[(size_t)n * 4 + q], f8);  // self-loop
    }
    int e = e0;
    // -------- phase LO: sources < N/2 (3.2MB set, L2-resident) --------
    for (; e + 3 < es; e += 4) {
        int s0 = __builtin_nontemporal_load(col + e);
        int s1 = __builtin_nontemporal_load(col + e + 1);
        int s2 = __builtin_nontemporal_load(col + e + 2);
        int s3 = __builtin_nontemporal_load(col + e + 3);
        h8 h0 = gin[(size_t)s0 * 4 + q];
        h8 h1 = gin[(size_t)s1 * 4 + q];
        h8 h2 = gin[(size_t)s2 * 4 + q];
        h8 h3 = gin[(size_t)s3 * 4 + q];
        a0 += __builtin_convertvector(h0, f8);
        a1 += __builtin_convertvector(h1, f8);
        a0 += __builtin_convertvector(h2, f8);
        a1 += __builtin_convertvector(h3, f8);
    }
    for (; e < es; ++e)
        a0 += __builtin_convertvector(gin[(size_t)__builtin_nontemporal_load(col + e) * 4 + q], f8);
    __syncthreads();   // phase boundary: align block's waves
    // -------- phase HI: sources >= N/2 --------
    for (; e + 3 < e1; e += 4) {
        int s0 = __builtin_nontemporal_load(col + e);
        int s1 = __builtin_nontemporal_load(col + e + 1);
        int s2 = __builtin_nontemporal_load(col + e + 2);
        int s3 = __builtin_nontemporal_load(col + e + 3);
        h8 h0 = gin[(size_t)s0 * 4 + q];
        h8 h1 = gin[(size_t)s1 * 4 + q];
        h8 h2 = gin[(size_t)s2 * 4 + q];
        h8 h3 = gin[(size_t)s3 * 4 + q];
        a0 += __builtin_convertvector(h0, f8);
        a1 += __builtin_convertvector(h1, f8);
        a0 += __builtin_convertvector(h2, f8);
        a1 += __builtin_convertvector(h3, f8);
    }
    for (; e < e1; ++e)
        a0 += __builtin_convertvector(gin[(size_t)__builtin_nontemporal_load(col + e) * 4 + q], f8);
    if (act) {
        float sc = di * di;
        f8 rr = sc * (a0 + a1);
        __builtin_nontemporal_store(__builtin_convertvector(rr, h8),
                                    &gout[(size_t)n * 4 + q]);
    }
}

// ---------- Final hop FUSED with linear; two-phase gather + conflict-free
// ---------- epilogue. Block = 64 nodes x 4 lanes, then 16 passes x 4 nodes.
__global__ __launch_bounds__(256) void k_hop3_linear(const i4* __restrict__ nrec,
                                                     const int* __restrict__ col,
                                                     const h8* __restrict__ gin,
                                                     const float* __restrict__ W,
                                                     const float* __restrict__ bias,
                                                     float* __restrict__ out, int N) {
    __shared__ float Wl[F_OUT][F_IN + 1];   // 8.4 KB
    __shared__ float hl[64][F_IN + 1];      // 8.4 KB
    int tid = threadIdx.x;
    for (int idx = tid; idx < F_OUT * F_IN; idx += 256)
        Wl[idx >> 5][idx & 31] = W[idx];

    int nl = tid >> 2;                 // 0..63 local node
    int q = tid & 3;
    int nbase = blockIdx.x * 64;
    int n = nbase + nl;
    bool act = n < N;
    int e0 = 0, e1 = 0, es = 0;
    float di = 0.f;
    f8 a0 = {0.f, 0.f, 0.f, 0.f, 0.f, 0.f, 0.f, 0.f};
    f8 a1 = {0.f, 0.f, 0.f, 0.f, 0.f, 0.f, 0.f, 0.f};
    if (act) {
        i4 r = __builtin_nontemporal_load(&nrec[n]);
        e0 = r.x; e1 = r.y; es = r.w;
        di = __int_as_float(r.z);
        a0 = __builtin_convertvector(gin[(size_t)n * 4 + q], f8);
    }
    int e = e0;
    // phase LO
    for (; e + 3 < es; e += 4) {
        int s0 = __builtin_nontemporal_load(col + e);
        int s1 = __builtin_nontemporal_load(col + e + 1);
        int s2 = __builtin_nontemporal_load(col + e + 2);
        int s3 = __builtin_nontemporal_load(col + e + 3);
        h8 h0 = gin[(size_t)s0 * 4 + q];
        h8 h1 = gin[(size_t)s1 * 4 + q];
        h8 h2 = gin[(size_t)s2 * 4 + q];
        h8 h3 = gin[(size_t)s3 * 4 + q];
        a0 += __builtin_convertvector(h0, f8);
        a1 += __builtin_convertvector(h1, f8);
        a0 += __builtin_convertvector(h2, f8);
        a1 += __builtin_convertvector(h3, f8);
    }
    for (; e < es; ++e)
        a0 += __builtin_convertvector(gin[(size_t)__builtin_nontemporal_load(col + e) * 4 + q], f8);
    __syncthreads();   // phase boundary
    // phase HI
    for (; e + 3 < e1; e += 4) {
        int s0 = __builtin_nontemporal_load(col + e);
        int s1 = __builtin_nontemporal_load(col + e + 1);
        int s2 = __builtin_nontemporal_load(col + e + 2);
        int s3 = __builtin_nontemporal_load(col + e + 3);
        h8 h0 = gin[(size_t)s0 * 4 + q];
        h8 h1 = gin[(size_t)s1 * 4 + q];
        h8 h2 = gin[(size_t)s2 * 4 + q];
        h8 h3 = gin[(size_t)s3 * 4 + q];
        a0 += __builtin_convertvector(h0, f8);
        a1 += __builtin_convertvector(h1, f8);
        a0 += __builtin_convertvector(h2, f8);
        a1 += __builtin_convertvector(h3, f8);
    }
    for (; e < e1; ++e)
        a0 += __builtin_convertvector(gin[(size_t)__builtin_nontemporal_load(col + e) * 4 + q], f8);
    if (act) {
        f8 rr = di * (a0 + a1);
#pragma unroll
        for (int i = 0; i < 8; ++i) hl[nl][q * 8 + i] = rr[i];
    }
    __syncthreads();
    // W row -> registers, conflict-free: lanes o=0..63 read Wl[o][f], bank (o+f)%32
    int o = tid & 63;
    float wreg[F_IN];
#pragma unroll
    for (int f = 0; f < F_IN; ++f) wreg[f] = Wl[o][f];
    float bv = bias[o];
    // 16 passes x 4 nodes: node index wave-uniform -> hl reads broadcast
    int nchunk = tid >> 6;  // 0..3
#pragma unroll
    for (int p = 0; p < 16; ++p) {
        int nloc = p * 4 + nchunk;
        int nn = nbase + nloc;
        if (nn < N) {
            float acc = bv;
#pragma unroll
            for (int f = 0; f < F_IN; ++f) acc += hl[nloc][f] * wreg[f];
            out[(size_t)nn * F_OUT + o] = acc;
        }
    }
}

extern "C" void kernel_launch(void* const* d_in, const int* in_sizes, int n_in,
                              void* d_out, int out_size, void* d_ws, size_t ws_size,
                              hipStream_t stream) {
    const float* x  = (const float*)d_in[0];
    const int*   ei = (const int*)d_in[1];   // [2,E] int32: src row then dst row
    const float* W  = (const float*)d_in[2];
    const float* b  = (const float*)d_in[3];
    float* out = (float*)d_out;

    const int N = in_sizes[0] / F_IN;
    const int E = in_sizes[1] / 2;
    const int NSB  = (N + (1 << SB_SHIFT) - 1) >> SB_SHIFT;   // 13
    const int NSUB = (N + SUB - 1) >> SUB_SHIFT;              // 391
    const int Nhalf = N >> 1;

    // ws: scur(16) | subcur(16*32) | nrec(16B*N) | b1 | b2 | col | hA hB
    int* scur   = (int*)d_ws;
    int* subcur = scur + NSB_MAX;
    i4* nrec    = (i4*)(((uintptr_t)(subcur + NSB_MAX * SPS) + 255) & ~(uintptr_t)255);
    unsigned* b1 = (unsigned*)(((uintptr_t)(nrec + N) + 255) & ~(uintptr_t)255);
    unsigned* b2 = b1 + (size_t)NSB_MAX * SCAP;
    int* col     = (int*)(b2 + (size_t)NSB_MAX * SPS * SUBCAP);
    _Float16* hA = (_Float16*)(((uintptr_t)(col + (size_t)NSB_MAX * SPS * SUBCAP) + 255)
                               & ~(uintptr_t)255);
    _Float16* hB = hA + (size_t)N * F_IN;

    const int B = 256;
    dim3 blk(B);

    hipMemsetAsync(scur, 0, (NSB_MAX + NSB_MAX * SPS) * sizeof(int), stream);

    // two-level radix partition
    k_bin1<<<dim3((E + EPB1 - 1) / EPB1), blk, 0, stream>>>(ei, scur, b1, E);
    k_bin2<<<dim3(NSB * BPS), blk, 0, stream>>>(b1, scur, subcur, b2);

    // per-sub counting sort (lo|hi partitioned) + fused prescale (g0 -> hA)
    k_fill3<<<dim3(NSUB), blk, 0, stream>>>(b2, subcur, (const f4*)x,
                                            nrec, col, (h8*)hA, N, Nhalf);

    // hops 1,2 (ping-pong): hA -> hB -> hA
    dim3 gHop(((size_t)N * 4 + B - 1) / B);
    k_hop_gather<<<gHop, blk, 0, stream>>>(nrec, col, (const h8*)hA, (h8*)hB, N);
    k_hop_gather<<<gHop, blk, 0, stream>>>(nrec, col, (const h8*)hB, (h8*)hA, N);

    // hop 3 fused with linear: hA -> out
    k_hop3_linear<<<dim3((N + 63) / 64), blk, 0, stream>>>(nrec, col,
                                                           (const h8*)hA, W, b, out, N);
}

// Round 5
// 200.620 us; speedup vs baseline: 1.0596x; 1.0596x over previous
//
#include <hip/hip_runtime.h>

// SGConv: K=3 hops of \hat{A} x (symmetric gcn_norm w/ self-loops), then Linear.
// N=100000, E=1600000, F_in=32, F_out=64.
// Round 21: exact revert to R17 (measured best, 200.3us).
// Post-R20 model (from per-kernel counters): hop kernels run at the
// STRUCTURAL MINIMUM of L2-fill traffic (FETCH 44.6MB == distinct-lines
// floor of ~44MB: 8 XCDs x 86K distinct 64B lines/hop) on a saturated
// random-line fill path (~0.8 lines/cy/XCD, 1.55 TB/s effective). All
// concurrency/latency interventions (R15/R17/R18/R19/R20) were neutral or
// negative; time moves only with touch/fill count, which is already minimal
// for fp16 64B rows (precision floor). Keep: two-level radix build,
// per-wave replicated bin counters, fill3+prescale fusion, 4 lanes/node
// 16B gathers, unroll-4 hops, fused hop3+linear conflict-free epilogue.

#define F_IN 32
#define F_OUT 64
#define SB_SHIFT 13                  // 8192 nodes per super-bucket
#define NSB_MAX 16
#define SUB_SHIFT 8                  // 256 nodes per sub-bucket
#define SUB (1 << SUB_SHIFT)
#define SPS 32                       // subs per super (8192/256)
#define EPB1 2048
#define EPB2 4096
#define SCAP 147456                  // super slab cap (mean 131072, sd ~347)
#define SUBCAP 6144                  // sub slab cap (mean 4096, sd ~64)
#define BPS (SCAP / EPB2)            // 36 blocks per super in k_bin2

typedef float f4 __attribute__((ext_vector_type(4)));
typedef float f8 __attribute__((ext_vector_type(8)));
typedef _Float16 h4 __attribute__((ext_vector_type(4)));   // 8B
typedef _Float16 h8 __attribute__((ext_vector_type(8)));   // 16B
typedef int i2 __attribute__((ext_vector_type(2)));

// ---------- Level-1 bin: 13 supers; per-wave replicated hist/cursors ----------
__global__ __launch_bounds__(256) void k_bin1(const int* __restrict__ ei,
                                              int* __restrict__ scur,
                                              unsigned* __restrict__ b1, int E) {
    __shared__ unsigned stage[EPB1];          // 8 KB
    __shared__ unsigned char bidl[EPB1];      // 2 KB
    __shared__ int h4w[4][NSB_MAX];           // per-wave hist
    __shared__ int f4w[4][NSB_MAX];           // per-wave cursors
    __shared__ int lscanx[NSB_MAX], lbase[NSB_MAX];
    unsigned rec[EPB1 / 256];
    int      bk[EPB1 / 256];
    int tid = threadIdx.x;
    int wv = tid >> 6;
    int base = blockIdx.x * EPB1;
    int cnt = E - base; if (cnt > EPB1) cnt = EPB1;

    if (tid < 64) { h4w[tid >> 4][tid & 15] = 0; }
    __syncthreads();
#pragma unroll
    for (int k = 0; k < EPB1 / 256; ++k) {
        int i = base + k * 256 + tid;
        bk[k] = -1;
        if (i < E) {
            unsigned s = (unsigned)ei[i];
            unsigned d = (unsigned)ei[E + i];
            int b = d >> SB_SHIFT;
            rec[k] = (s << SB_SHIFT) | (d & ((1u << SB_SHIFT) - 1));
            bk[k] = b;
            atomicAdd(&h4w[wv][b], 1);
        }
    }
    __syncthreads();
    if (tid < 16) {
        int t0 = h4w[0][tid], t1 = h4w[1][tid], t2 = h4w[2][tid], t3 = h4w[3][tid];
        int tot = t0 + t1 + t2 + t3;
        int inc = tot;
#pragma unroll
        for (int off = 1; off < 16; off <<= 1) {
            int t = __shfl_up(inc, off);
            if (tid >= off) inc += t;
        }
        int excl = inc - tot;
        lscanx[tid] = excl;
        lbase[tid] = tot ? atomicAdd(&scur[tid], tot) : 0;
        f4w[0][tid] = excl;
        f4w[1][tid] = excl + t0;
        f4w[2][tid] = excl + t0 + t1;
        f4w[3][tid] = excl + t0 + t1 + t2;
    }
    __syncthreads();
#pragma unroll
    for (int k = 0; k < EPB1 / 256; ++k) {
        if (bk[k] >= 0) {
            int loc = atomicAdd(&f4w[wv][bk[k]], 1);
            stage[loc] = rec[k];
            bidl[loc] = (unsigned char)bk[k];
        }
    }
    __syncthreads();
    for (int k = 0; k < EPB1 / 256; ++k) {
        int idx = k * 256 + tid;
        if (idx < cnt) {
            int b = bidl[idx];
            b1[(size_t)b * SCAP + lbase[b] + (idx - lscanx[b])] = stage[idx];
        }
    }
}

// ---------- Level-2 bin: 32 subs per super; per-wave replicated ----------
__global__ __launch_bounds__(256) void k_bin2(const unsigned* __restrict__ b1,
                                              const int* __restrict__ scur,
                                              int* __restrict__ subcur,
                                              unsigned* __restrict__ b2) {
    int sb = blockIdx.x / BPS;
    int base = (blockIdx.x % BPS) * EPB2;
    int count = scur[sb];
    if (base >= count) return;
    int cnt = count - base; if (cnt > EPB2) cnt = EPB2;
    const unsigned* src = b1 + (size_t)sb * SCAP + base;

    __shared__ unsigned stage[EPB2];          // 16 KB
    __shared__ unsigned char bidl[EPB2];      // 4 KB
    __shared__ int h4w[4][SPS];
    __shared__ int f4w[4][SPS];
    __shared__ int lscanx[SPS], lbase[SPS];
    unsigned rec[EPB2 / 256];
    int tid = threadIdx.x;
    int wv = tid >> 6;
    if (tid < 128) h4w[tid >> 5][tid & 31] = 0;
    __syncthreads();
#pragma unroll
    for (int k = 0; k < EPB2 / 256; ++k) {
        int i = k * 256 + tid;
        rec[k] = 0xFFFFFFFFu;
        if (i < cnt) {
            unsigned r = src[i];
            rec[k] = r;
            atomicAdd(&h4w[wv][(r >> SUB_SHIFT) & (SPS - 1)], 1);
        }
    }
    __syncthreads();
    if (tid < 32) {
        int t0 = h4w[0][tid], t1 = h4w[1][tid], t2 = h4w[2][tid], t3 = h4w[3][tid];
        int tot = t0 + t1 + t2 + t3;
        int inc = tot;
#pragma unroll
        for (int off = 1; off < 32; off <<= 1) {
            int t = __shfl_up(inc, off);
            if (tid >= off) inc += t;
        }
        int excl = inc - tot;
        lscanx[tid] = excl;
        lbase[tid] = tot ? atomicAdd(&subcur[sb * SPS + tid], tot) : 0;
        f4w[0][tid] = excl;
        f4w[1][tid] = excl + t0;
        f4w[2][tid] = excl + t0 + t1;
        f4w[3][tid] = excl + t0 + t1 + t2;
    }
    __syncthreads();
#pragma unroll
    for (int k = 0; k < EPB2 / 256; ++k) {
        if (rec[k] != 0xFFFFFFFFu) {
            int b = (rec[k] >> SUB_SHIFT) & (SPS - 1);
            int loc = atomicAdd(&f4w[wv][b], 1);
            stage[loc] = rec[k];
            bidl[loc] = (unsigned char)b;
        }
    }
    __syncthreads();
    for (int k = 0; k < EPB2 / 256; ++k) {
        int idx = k * 256 + tid;
        if (idx < cnt) {
            unsigned r = stage[idx];
            int b = bidl[idx];
            unsigned packed = ((r >> SB_SHIFT) << SUB_SHIFT) | (r & (SUB - 1));
            b2[(size_t)(sb * SPS + b) * SUBCAP + lbase[b] + (idx - lscanx[b])] = packed;
        }
    }
}

// ---------- fill3: one 256-thr block per 256-node sub + fused prescale ----------
__global__ __launch_bounds__(256) void k_fill3(const unsigned* __restrict__ b2,
                                               const int* __restrict__ subcur,
                                               const f4* __restrict__ x,
                                               float* __restrict__ dinv,
                                               i2* __restrict__ rp2,
                                               int* __restrict__ col,
                                               h8* __restrict__ g0, int N) {
    __shared__ unsigned stage[SUBCAP];        // 24 KB
    __shared__ int h[SUB];
    __shared__ float dl[SUB];
    __shared__ int wsum[4];
    int tid = threadIdx.x;
    int g = blockIdx.x;
    int count = subcur[g];
    int sbase = g * SUBCAP;
    int n0 = g << SUB_SHIFT;

    h[tid] = 0;
    for (int e = tid; e < count; e += 256) stage[e] = b2[(size_t)sbase + e];
    __syncthreads();
    for (int e = tid; e < count; e += 256) atomicAdd(&h[stage[e] & (SUB - 1)], 1);
    __syncthreads();

    int deg = h[tid];
    int lane = tid & 63, wid = tid >> 6;
    int inc = deg;
#pragma unroll
    for (int off = 1; off < 64; off <<= 1) {
        int t = __shfl_up(inc, off);
        if (lane >= off) inc += t;
    }
    if (lane == 63) wsum[wid] = inc;
    __syncthreads();
    if (wid == 0) {
        int v = (lane < 4) ? wsum[lane] : 0;
#pragma unroll
        for (int off = 1; off < 4; off <<= 1) {
            int t = __shfl_up(v, off);
            if (lane >= off) v += t;
        }
        if (lane < 4) wsum[lane] = v;
    }
    __syncthreads();
    int incl = inc + (wid ? wsum[wid - 1] : 0);
    int excl = incl - deg;

    int node = n0 + tid;
    float di = rsqrtf(1.0f + (float)deg);
    dl[tid] = di;
    if (node < N) {
        dinv[node] = di;
        rp2[node] = (i2){sbase + excl, sbase + incl};
    }
    h[tid] = excl;
    __syncthreads();

    for (int e = tid; e < count; e += 256) {
        unsigned r = stage[e];
        int slot = sbase + atomicAdd(&h[r & (SUB - 1)], 1);
        col[slot] = (int)(r >> SUB_SHIFT);
    }

    // fused prescale for this block's nodes: g0 = fp16(dinv .* x), 16B stores
    for (int idx = tid; idx < SUB * 4; idx += 256) {
        int nl = idx >> 2;
        int q = idx & 3;
        int node2 = n0 + nl;
        if (node2 < N) {
            int gi = node2 * 8 + q * 2;
            f4 vlo = dl[nl] * x[gi];
            f4 vhi = dl[nl] * x[gi + 1];
            f8 v = __builtin_shufflevector(vlo, vhi, 0, 1, 2, 3, 4, 5, 6, 7);
            g0[(size_t)node2 * 4 + q] = __builtin_convertvector(v, h8);
        }
    }
}

// ---------- Mid hop (hops 1,2): 4 lanes/row, 16B loads, unroll-4 ----------
__global__ __launch_bounds__(256) void k_hop_gather(const i2* __restrict__ rp2,
                                                    const int* __restrict__ col,
                                                    const float* __restrict__ dinv,
                                                    const h8* __restrict__ gin,
                                                    h8* __restrict__ gout, int N) {
    int t = blockIdx.x * blockDim.x + threadIdx.x;
    int n = t >> 2;
    if (n >= N) return;
    int q = t & 3;
    i2 r2 = rp2[n];
    int e0 = r2.x, e1 = r2.y;
    f8 a0 = __builtin_convertvector(gin[(size_t)n * 4 + q], f8);  // self-loop
    f8 a1 = {0.f, 0.f, 0.f, 0.f, 0.f, 0.f, 0.f, 0.f};
    int e = e0;
    for (; e + 3 < e1; e += 4) {
        int s0 = col[e], s1 = col[e + 1], s2 = col[e + 2], s3 = col[e + 3];
        h8 h0 = gin[(size_t)s0 * 4 + q];
        h8 h1 = gin[(size_t)s1 * 4 + q];
        h8 h2 = gin[(size_t)s2 * 4 + q];
        h8 h3 = gin[(size_t)s3 * 4 + q];
        a0 += __builtin_convertvector(h0, f8);
        a1 += __builtin_convertvector(h1, f8);
        a0 += __builtin_convertvector(h2, f8);
        a1 += __builtin_convertvector(h3, f8);
    }
    for (; e < e1; ++e) a0 += __builtin_convertvector(gin[(size_t)col[e] * 4 + q], f8);
    float di = dinv[n];
    float sc = di * di;
    f8 r = sc * (a0 + a1);
    gout[(size_t)n * 4 + q] = __builtin_convertvector(r, h8);
}

// ---------- Final hop FUSED with linear; conflict-free epilogue ----------
// Block = 256 thr = 64 nodes x 4 lanes (gather), then 16 passes of 4 nodes x 64 o.
__global__ __launch_bounds__(256) void k_hop3_linear(const i2* __restrict__ rp2,
                                                     const int* __restrict__ col,
                                                     const float* __restrict__ dinv,
                                                     const h8* __restrict__ gin,
                                                     const float* __restrict__ W,
                                                     const float* __restrict__ bias,
                                                     float* __restrict__ out, int N) {
    __shared__ float Wl[F_OUT][F_IN + 1];   // 8.4 KB
    __shared__ float hl[64][F_IN + 1];      // 8.4 KB
    int tid = threadIdx.x;
    for (int idx = tid; idx < F_OUT * F_IN; idx += 256)
        Wl[idx >> 5][idx & 31] = W[idx];

    int nl = tid >> 2;                 // 0..63 local node
    int q = tid & 3;
    int nbase = blockIdx.x * 64;
    int n = nbase + nl;
    if (n < N) {
        i2 r2 = rp2[n];
        int e0 = r2.x, e1 = r2.y;
        f8 a0 = __builtin_convertvector(gin[(size_t)n * 4 + q], f8);
        f8 a1 = {0.f, 0.f, 0.f, 0.f, 0.f, 0.f, 0.f, 0.f};
        int e = e0;
        for (; e + 3 < e1; e += 4) {
            int s0 = col[e], s1 = col[e + 1], s2 = col[e + 2], s3 = col[e + 3];
            h8 h0 = gin[(size_t)s0 * 4 + q];
            h8 h1 = gin[(size_t)s1 * 4 + q];
            h8 h2 = gin[(size_t)s2 * 4 + q];
            h8 h3 = gin[(size_t)s3 * 4 + q];
            a0 += __builtin_convertvector(h0, f8);
            a1 += __builtin_convertvector(h1, f8);
            a0 += __builtin_convertvector(h2, f8);
            a1 += __builtin_convertvector(h3, f8);
        }
        for (; e < e1; ++e) a0 += __builtin_convertvector(gin[(size_t)col[e] * 4 + q], f8);
        float di = dinv[n];
        f8 r = di * (a0 + a1);
#pragma unroll
        for (int i = 0; i < 8; ++i) hl[nl][q * 8 + i] = r[i];
    }
    __syncthreads();
    // W row -> registers, conflict-free: lanes o=0..63 read Wl[o][f], bank (o+f)%32
    int o = tid & 63;
    float wreg[F_IN];
#pragma unroll
    for (int f = 0; f < F_IN; ++f) wreg[f] = Wl[o][f];
    float bv = bias[o];
    // 16 passes x 4 nodes: node index wave-uniform -> hl reads broadcast
    int nchunk = tid >> 6;  // 0..3
#pragma unroll
    for (int p = 0; p < 16; ++p) {
        int nloc = p * 4 + nchunk;
        int nn = nbase + nloc;
        if (nn < N) {
            float acc = bv;
#pragma unroll
            for (int f = 0; f < F_IN; ++f) acc += hl[nloc][f] * wreg[f];
            out[(size_t)nn * F_OUT + o] = acc;
        }
    }
}

extern "C" void kernel_launch(void* const* d_in, const int* in_sizes, int n_in,
                              void* d_out, int out_size, void* d_ws, size_t ws_size,
                              hipStream_t stream) {
    const float* x  = (const float*)d_in[0];
    const int*   ei = (const int*)d_in[1];   // [2,E] int32: src row then dst row
    const float* W  = (const float*)d_in[2];
    const float* b  = (const float*)d_in[3];
    float* out = (float*)d_out;

    const int N = in_sizes[0] / F_IN;
    const int E = in_sizes[1] / 2;
    const int NSB  = (N + (1 << SB_SHIFT) - 1) >> SB_SHIFT;   // 13
    const int NSUB = (N + SUB - 1) >> SUB_SHIFT;              // 391

    // ws: scur(16) | subcur(16*32) | rp2(2N) | dinv(N) | b1 | b2 | col | hA hB
    int* scur   = (int*)d_ws;
    int* subcur = scur + NSB_MAX;
    i2*  rp2    = (i2*)(subcur + NSB_MAX * SPS);
    float* dinv = (float*)(rp2 + N);
    unsigned* b1 = (unsigned*)(((uintptr_t)(dinv + N) + 255) & ~(uintptr_t)255);
    unsigned* b2 = b1 + (size_t)NSB_MAX * SCAP;
    int* col     = (int*)(b2 + (size_t)NSB_MAX * SPS * SUBCAP);
    _Float16* hA = (_Float16*)(((uintptr_t)(col + (size_t)NSB_MAX * SPS * SUBCAP) + 255)
                               & ~(uintptr_t)255);
    _Float16* hB = hA + (size_t)N * F_IN;

    const int B = 256;
    dim3 blk(B);

    hipMemsetAsync(scur, 0, (NSB_MAX + NSB_MAX * SPS) * sizeof(int), stream);

    // two-level radix partition
    k_bin1<<<dim3((E + EPB1 - 1) / EPB1), blk, 0, stream>>>(ei, scur, b1, E);
    k_bin2<<<dim3(NSB * BPS), blk, 0, stream>>>(b1, scur, subcur, b2);

    // per-sub counting sort + fused prescale (g0 -> hA)
    k_fill3<<<dim3(NSUB), blk, 0, stream>>>(b2, subcur, (const f4*)x,
                                            dinv, rp2, col, (h8*)hA, N);

    // hops 1,2 (ping-pong): hA -> hB -> hA
    dim3 gHop(((size_t)N * 4 + B - 1) / B);
    k_hop_gather<<<gHop, blk, 0, stream>>>(rp2, col, dinv, (const h8*)hA, (h8*)hB, N);
    k_hop_gather<<<gHop, blk, 0, stream>>>(rp2, col, dinv, (const h8*)hB, (h8*)hA, N);

    // hop 3 fused with linear: hA -> out
    k_hop3_linear<<<dim3((N + 63) / 64), blk, 0, stream>>>(rp2, col, dinv,
                                                           (const h8*)hA, W, b, out, N);
}

// Round 6
// 200.393 us; speedup vs baseline: 1.0608x; 1.0011x over previous
//
#include <hip/hip_runtime.h>
#include <hip/hip_cooperative_groups.h>

namespace cg = cooperative_groups;

// SGConv: K=3 hops of \hat{A} x (symmetric gcn_norm w/ self-loops), then Linear.
// N=100000, E=1600000, F_in=32, F_out=64.
// Round 22: fuse the 3 hop kernels into ONE cooperative kernel (grid.sync
// between hops). Model (R17..R21): gather pipe services scattered 64B line
// requests at a fixed rate (~15 lines/cy device); requests already at the
// 1/edge structural minimum (64B rows, 4x16B lanes coalesce); FETCH moved
// 35% (R20 vs R21) with zero time change -> not fill-bound; only touch
// count moves time. Hop floor ~136us. Remaining lever: kernel-boundary
// overhead (7 dispatches). Mid-hops and hop3+linear share the same grid
// mapping (1563 blocks x 64 nodes x 4 lanes) -> fuse, load rp2/dinv once
// into registers, preload W during hop1. Fallback to separate launches if
// cooperative co-residency check fails.
// Keep: two-level radix build, per-wave replicated bin counters, fill3+
// prescale fusion, 4 lanes/node 16B gathers, unroll-4, conflict-free
// linear epilogue.

#define F_IN 32
#define F_OUT 64
#define SB_SHIFT 13                  // 8192 nodes per super-bucket
#define NSB_MAX 16
#define SUB_SHIFT 8                  // 256 nodes per sub-bucket
#define SUB (1 << SUB_SHIFT)
#define SPS 32                       // subs per super (8192/256)
#define EPB1 2048
#define EPB2 4096
#define SCAP 147456                  // super slab cap (mean 131072, sd ~347)
#define SUBCAP 6144                  // sub slab cap (mean 4096, sd ~64)
#define BPS (SCAP / EPB2)            // 36 blocks per super in k_bin2

typedef float f4 __attribute__((ext_vector_type(4)));
typedef float f8 __attribute__((ext_vector_type(8)));
typedef _Float16 h8 __attribute__((ext_vector_type(8)));   // 16B
typedef int i2 __attribute__((ext_vector_type(2)));

// ---------- Level-1 bin: 13 supers; per-wave replicated hist/cursors ----------
__global__ __launch_bounds__(256) void k_bin1(const int* __restrict__ ei,
                                              int* __restrict__ scur,
                                              unsigned* __restrict__ b1, int E) {
    __shared__ unsigned stage[EPB1];          // 8 KB
    __shared__ unsigned char bidl[EPB1];      // 2 KB
    __shared__ int h4w[4][NSB_MAX];           // per-wave hist
    __shared__ int f4w[4][NSB_MAX];           // per-wave cursors
    __shared__ int lscanx[NSB_MAX], lbase[NSB_MAX];
    unsigned rec[EPB1 / 256];
    int      bk[EPB1 / 256];
    int tid = threadIdx.x;
    int wv = tid >> 6;
    int base = blockIdx.x * EPB1;
    int cnt = E - base; if (cnt > EPB1) cnt = EPB1;

    if (tid < 64) { h4w[tid >> 4][tid & 15] = 0; }
    __syncthreads();
#pragma unroll
    for (int k = 0; k < EPB1 / 256; ++k) {
        int i = base + k * 256 + tid;
        bk[k] = -1;
        if (i < E) {
            unsigned s = (unsigned)ei[i];
            unsigned d = (unsigned)ei[E + i];
            int b = d >> SB_SHIFT;
            rec[k] = (s << SB_SHIFT) | (d & ((1u << SB_SHIFT) - 1));
            bk[k] = b;
            atomicAdd(&h4w[wv][b], 1);
        }
    }
    __syncthreads();
    if (tid < 16) {
        int t0 = h4w[0][tid], t1 = h4w[1][tid], t2 = h4w[2][tid], t3 = h4w[3][tid];
        int tot = t0 + t1 + t2 + t3;
        int inc = tot;
#pragma unroll
        for (int off = 1; off < 16; off <<= 1) {
            int t = __shfl_up(inc, off);
            if (tid >= off) inc += t;
        }
        int excl = inc - tot;
        lscanx[tid] = excl;
        lbase[tid] = tot ? atomicAdd(&scur[tid], tot) : 0;
        f4w[0][tid] = excl;
        f4w[1][tid] = excl + t0;
        f4w[2][tid] = excl + t0 + t1;
        f4w[3][tid] = excl + t0 + t1 + t2;
    }
    __syncthreads();
#pragma unroll
    for (int k = 0; k < EPB1 / 256; ++k) {
        if (bk[k] >= 0) {
            int loc = atomicAdd(&f4w[wv][bk[k]], 1);
            stage[loc] = rec[k];
            bidl[loc] = (unsigned char)bk[k];
        }
    }
    __syncthreads();
    for (int k = 0; k < EPB1 / 256; ++k) {
        int idx = k * 256 + tid;
        if (idx < cnt) {
            int b = bidl[idx];
            b1[(size_t)b * SCAP + lbase[b] + (idx - lscanx[b])] = stage[idx];
        }
    }
}

// ---------- Level-2 bin: 32 subs per super; per-wave replicated ----------
__global__ __launch_bounds__(256) void k_bin2(const unsigned* __restrict__ b1,
                                              const int* __restrict__ scur,
                                              int* __restrict__ subcur,
                                              unsigned* __restrict__ b2) {
    int sb = blockIdx.x / BPS;
    int base = (blockIdx.x % BPS) * EPB2;
    int count = scur[sb];
    if (base >= count) return;
    int cnt = count - base; if (cnt > EPB2) cnt = EPB2;
    const unsigned* src = b1 + (size_t)sb * SCAP + base;

    __shared__ unsigned stage[EPB2];          // 16 KB
    __shared__ unsigned char bidl[EPB2];      // 4 KB
    __shared__ int h4w[4][SPS];
    __shared__ int f4w[4][SPS];
    __shared__ int lscanx[SPS], lbase[SPS];
    unsigned rec[EPB2 / 256];
    int tid = threadIdx.x;
    int wv = tid >> 6;
    if (tid < 128) h4w[tid >> 5][tid & 31] = 0;
    __syncthreads();
#pragma unroll
    for (int k = 0; k < EPB2 / 256; ++k) {
        int i = k * 256 + tid;
        rec[k] = 0xFFFFFFFFu;
        if (i < cnt) {
            unsigned r = src[i];
            rec[k] = r;
            atomicAdd(&h4w[wv][(r >> SUB_SHIFT) & (SPS - 1)], 1);
        }
    }
    __syncthreads();
    if (tid < 32) {
        int t0 = h4w[0][tid], t1 = h4w[1][tid], t2 = h4w[2][tid], t3 = h4w[3][tid];
        int tot = t0 + t1 + t2 + t3;
        int inc = tot;
#pragma unroll
        for (int off = 1; off < 32; off <<= 1) {
            int t = __shfl_up(inc, off);
            if (tid >= off) inc += t;
        }
        int excl = inc - tot;
        lscanx[tid] = excl;
        lbase[tid] = tot ? atomicAdd(&subcur[sb * SPS + tid], tot) : 0;
        f4w[0][tid] = excl;
        f4w[1][tid] = excl + t0;
        f4w[2][tid] = excl + t0 + t1;
        f4w[3][tid] = excl + t0 + t1 + t2;
    }
    __syncthreads();
#pragma unroll
    for (int k = 0; k < EPB2 / 256; ++k) {
        if (rec[k] != 0xFFFFFFFFu) {
            int b = (rec[k] >> SUB_SHIFT) & (SPS - 1);
            int loc = atomicAdd(&f4w[wv][b], 1);
            stage[loc] = rec[k];
            bidl[loc] = (unsigned char)b;
        }
    }
    __syncthreads();
    for (int k = 0; k < EPB2 / 256; ++k) {
        int idx = k * 256 + tid;
        if (idx < cnt) {
            unsigned r = stage[idx];
            int b = bidl[idx];
            unsigned packed = ((r >> SB_SHIFT) << SUB_SHIFT) | (r & (SUB - 1));
            b2[(size_t)(sb * SPS + b) * SUBCAP + lbase[b] + (idx - lscanx[b])] = packed;
        }
    }
}

// ---------- fill3: one 256-thr block per 256-node sub + fused prescale ----------
__global__ __launch_bounds__(256) void k_fill3(const unsigned* __restrict__ b2,
                                               const int* __restrict__ subcur,
                                               const f4* __restrict__ x,
                                               float* __restrict__ dinv,
                                               i2* __restrict__ rp2,
                                               int* __restrict__ col,
                                               h8* __restrict__ g0, int N) {
    __shared__ unsigned stage[SUBCAP];        // 24 KB
    __shared__ int h[SUB];
    __shared__ float dl[SUB];
    __shared__ int wsum[4];
    int tid = threadIdx.x;
    int g = blockIdx.x;
    int count = subcur[g];
    int sbase = g * SUBCAP;
    int n0 = g << SUB_SHIFT;

    h[tid] = 0;
    for (int e = tid; e < count; e += 256) stage[e] = b2[(size_t)sbase + e];
    __syncthreads();
    for (int e = tid; e < count; e += 256) atomicAdd(&h[stage[e] & (SUB - 1)], 1);
    __syncthreads();

    int deg = h[tid];
    int lane = tid & 63, wid = tid >> 6;
    int inc = deg;
#pragma unroll
    for (int off = 1; off < 64; off <<= 1) {
        int t = __shfl_up(inc, off);
        if (lane >= off) inc += t;
    }
    if (lane == 63) wsum[wid] = inc;
    __syncthreads();
    if (wid == 0) {
        int v = (lane < 4) ? wsum[lane] : 0;
#pragma unroll
        for (int off = 1; off < 4; off <<= 1) {
            int t = __shfl_up(v, off);
            if (lane >= off) v += t;
        }
        if (lane < 4) wsum[lane] = v;
    }
    __syncthreads();
    int incl = inc + (wid ? wsum[wid - 1] : 0);
    int excl = incl - deg;

    int node = n0 + tid;
    float di = rsqrtf(1.0f + (float)deg);
    dl[tid] = di;
    if (node < N) {
        dinv[node] = di;
        rp2[node] = (i2){sbase + excl, sbase + incl};
    }
    h[tid] = excl;
    __syncthreads();

    for (int e = tid; e < count; e += 256) {
        unsigned r = stage[e];
        int slot = sbase + atomicAdd(&h[r & (SUB - 1)], 1);
        col[slot] = (int)(r >> SUB_SHIFT);
    }

    // fused prescale for this block's nodes: g0 = fp16(dinv .* x), 16B stores
    for (int idx = tid; idx < SUB * 4; idx += 256) {
        int nl = idx >> 2;
        int q = idx & 3;
        int node2 = n0 + nl;
        if (node2 < N) {
            int gi = node2 * 8 + q * 2;
            f4 vlo = dl[nl] * x[gi];
            f4 vhi = dl[nl] * x[gi + 1];
            f8 v = __builtin_shufflevector(vlo, vhi, 0, 1, 2, 3, 4, 5, 6, 7);
            g0[(size_t)node2 * 4 + q] = __builtin_convertvector(v, h8);
        }
    }
}

// ---------- shared gather core: self-loop + unroll-4 neighbor sum ----------
__device__ __forceinline__ f8 gather_row(const h8* __restrict__ gin,
                                         int e0, int e1, const int* __restrict__ col,
                                         int n, int q) {
    f8 a0 = __builtin_convertvector(gin[(size_t)n * 4 + q], f8);  // self-loop
    f8 a1 = {0.f, 0.f, 0.f, 0.f, 0.f, 0.f, 0.f, 0.f};
    int e = e0;
    for (; e + 3 < e1; e += 4) {
        int s0 = col[e], s1 = col[e + 1], s2 = col[e + 2], s3 = col[e + 3];
        h8 h0 = gin[(size_t)s0 * 4 + q];
        h8 h1 = gin[(size_t)s1 * 4 + q];
        h8 h2 = gin[(size_t)s2 * 4 + q];
        h8 h3 = gin[(size_t)s3 * 4 + q];
        a0 += __builtin_convertvector(h0, f8);
        a1 += __builtin_convertvector(h1, f8);
        a0 += __builtin_convertvector(h2, f8);
        a1 += __builtin_convertvector(h3, f8);
    }
    for (; e < e1; ++e) a0 += __builtin_convertvector(gin[(size_t)col[e] * 4 + q], f8);
    return a0 + a1;
}

// ---------- Fused hops 1-3 + linear, cooperative (grid.sync between hops) ----
// Block = 256 thr = 64 nodes x 4 lanes; epilogue 16 passes x 4 nodes x 64 o.
__global__ __launch_bounds__(256) void k_hops_fused(const i2* __restrict__ rp2,
                                                    const int* __restrict__ col,
                                                    const float* __restrict__ dinv,
                                                    h8* __restrict__ hA,
                                                    h8* __restrict__ hB,
                                                    const float* __restrict__ W,
                                                    const float* __restrict__ bias,
                                                    float* __restrict__ out, int N) {
    cg::grid_group grid = cg::this_grid();
    __shared__ float Wl[F_OUT][F_IN + 1];   // 8.4 KB
    __shared__ float hl[64][F_IN + 1];      // 8.4 KB
    int tid = threadIdx.x;
    for (int idx = tid; idx < F_OUT * F_IN; idx += 256)
        Wl[idx >> 5][idx & 31] = W[idx];     // overlaps hop1

    int nl = tid >> 2;                 // 0..63 local node
    int q = tid & 3;
    int nbase = blockIdx.x * 64;
    int n = nbase + nl;
    bool act = n < N;
    int e0 = 0, e1 = 0;
    float di = 0.f;
    if (act) {
        i2 r2 = rp2[n];
        e0 = r2.x; e1 = r2.y;
        di = dinv[n];
    }
    float sc = di * di;

    // ---- hop 1: hA -> hB
    if (act) {
        f8 acc = gather_row(hA, e0, e1, col, n, q);
        hB[(size_t)n * 4 + q] = __builtin_convertvector(sc * acc, h8);
    }
    grid.sync();
    // ---- hop 2: hB -> hA
    if (act) {
        f8 acc = gather_row(hB, e0, e1, col, n, q);
        hA[(size_t)n * 4 + q] = __builtin_convertvector(sc * acc, h8);
    }
    grid.sync();
    // ---- hop 3 (scale di, not di^2) staged to LDS
    if (act) {
        f8 acc = gather_row(hA, e0, e1, col, n, q);
        f8 r = di * acc;
#pragma unroll
        for (int i = 0; i < 8; ++i) hl[nl][q * 8 + i] = r[i];
    }
    __syncthreads();
    // ---- linear epilogue, conflict-free
    int o = tid & 63;
    float wreg[F_IN];
#pragma unroll
    for (int f = 0; f < F_IN; ++f) wreg[f] = Wl[o][f];
    float bv = bias[o];
    int nchunk = tid >> 6;  // 0..3
#pragma unroll
    for (int p = 0; p < 16; ++p) {
        int nloc = p * 4 + nchunk;
        int nn = nbase + nloc;
        if (nn < N) {
            float acc = bv;
#pragma unroll
            for (int f = 0; f < F_IN; ++f) acc += hl[nloc][f] * wreg[f];
            out[(size_t)nn * F_OUT + o] = acc;
        }
    }
}

// ---------- Fallback path (R17): separate mid-hop + fused hop3+linear ----------
__global__ __launch_bounds__(256) void k_hop_gather(const i2* __restrict__ rp2,
                                                    const int* __restrict__ col,
                                                    const float* __restrict__ dinv,
                                                    const h8* __restrict__ gin,
                                                    h8* __restrict__ gout, int N) {
    int t = blockIdx.x * blockDim.x + threadIdx.x;
    int n = t >> 2;
    if (n >= N) return;
    int q = t & 3;
    i2 r2 = rp2[n];
    f8 acc = gather_row(gin, r2.x, r2.y, col, n, q);
    float di = dinv[n];
    gout[(size_t)n * 4 + q] = __builtin_convertvector((di * di) * acc, h8);
}

__global__ __launch_bounds__(256) void k_hop3_linear(const i2* __restrict__ rp2,
                                                     const int* __restrict__ col,
                                                     const float* __restrict__ dinv,
                                                     const h8* __restrict__ gin,
                                                     const float* __restrict__ W,
                                                     const float* __restrict__ bias,
                                                     float* __restrict__ out, int N) {
    __shared__ float Wl[F_OUT][F_IN + 1];   // 8.4 KB
    __shared__ float hl[64][F_IN + 1];      // 8.4 KB
    int tid = threadIdx.x;
    for (int idx = tid; idx < F_OUT * F_IN; idx += 256)
        Wl[idx >> 5][idx & 31] = W[idx];

    int nl = tid >> 2;
    int q = tid & 3;
    int nbase = blockIdx.x * 64;
    int n = nbase + nl;
    if (n < N) {
        i2 r2 = rp2[n];
        f8 acc = gather_row(gin, r2.x, r2.y, col, n, q);
        f8 r = dinv[n] * acc;
#pragma unroll
        for (int i = 0; i < 8; ++i) hl[nl][q * 8 + i] = r[i];
    }
    __syncthreads();
    int o = tid & 63;
    float wreg[F_IN];
#pragma unroll
    for (int f = 0; f < F_IN; ++f) wreg[f] = Wl[o][f];
    float bv = bias[o];
    int nchunk = tid >> 6;
#pragma unroll
    for (int p = 0; p < 16; ++p) {
        int nloc = p * 4 + nchunk;
        int nn = nbase + nloc;
        if (nn < N) {
            float acc = bv;
#pragma unroll
            for (int f = 0; f < F_IN; ++f) acc += hl[nloc][f] * wreg[f];
            out[(size_t)nn * F_OUT + o] = acc;
        }
    }
}

extern "C" void kernel_launch(void* const* d_in, const int* in_sizes, int n_in,
                              void* d_out, int out_size, void* d_ws, size_t ws_size,
                              hipStream_t stream) {
    const float* x  = (const float*)d_in[0];
    const int*   ei = (const int*)d_in[1];   // [2,E] int32: src row then dst row
    const float* W  = (const float*)d_in[2];
    const float* b  = (const float*)d_in[3];
    float* out = (float*)d_out;

    const int N = in_sizes[0] / F_IN;
    const int E = in_sizes[1] / 2;
    const int NSB  = (N + (1 << SB_SHIFT) - 1) >> SB_SHIFT;   // 13
    const int NSUB = (N + SUB - 1) >> SUB_SHIFT;              // 391

    // ws: scur(16) | subcur(16*32) | rp2(2N) | dinv(N) | b1 | b2 | col | hA hB
    int* scur   = (int*)d_ws;
    int* subcur = scur + NSB_MAX;
    i2*  rp2    = (i2*)(subcur + NSB_MAX * SPS);
    float* dinv = (float*)(rp2 + N);
    unsigned* b1 = (unsigned*)(((uintptr_t)(dinv + N) + 255) & ~(uintptr_t)255);
    unsigned* b2 = b1 + (size_t)NSB_MAX * SCAP;
    int* col     = (int*)(b2 + (size_t)NSB_MAX * SPS * SUBCAP);
    _Float16* hA = (_Float16*)(((uintptr_t)(col + (size_t)NSB_MAX * SPS * SUBCAP) + 255)
                               & ~(uintptr_t)255);
    _Float16* hB = hA + (size_t)N * F_IN;

    const int B = 256;
    dim3 blk(B);

    hipMemsetAsync(scur, 0, (NSB_MAX + NSB_MAX * SPS) * sizeof(int), stream);

    // two-level radix partition
    k_bin1<<<dim3((E + EPB1 - 1) / EPB1), blk, 0, stream>>>(ei, scur, b1, E);
    k_bin2<<<dim3(NSB * BPS), blk, 0, stream>>>(b1, scur, subcur, b2);

    // per-sub counting sort + fused prescale (g0 -> hA)
    k_fill3<<<dim3(NSUB), blk, 0, stream>>>(b2, subcur, (const f4*)x,
                                            dinv, rp2, col, (h8*)hA, N);

    // fused hops + linear (cooperative), fallback to 3 launches if not co-resident
    dim3 gF((N + 63) / 64);                       // 1563 blocks, 64 nodes each
    int maxb = 0;
    hipError_t qerr = hipOccupancyMaxActiveBlocksPerMultiprocessor(
        &maxb, (const void*)k_hops_fused, B, 0);
    bool coop_ok = (qerr == hipSuccess) && ((long long)maxb * 256 >= (long long)gF.x);
    if (coop_ok) {
        const i2* rp2c = rp2;  const int* colc = col;  const float* dinvc = dinv;
        h8* hA8 = (h8*)hA;     h8* hB8 = (h8*)hB;
        const float* Wc = W;   const float* bc = b;
        float* outc = out;     int Nv = N;
        void* args[] = {(void*)&rp2c, (void*)&colc, (void*)&dinvc,
                        (void*)&hA8, (void*)&hB8, (void*)&Wc, (void*)&bc,
                        (void*)&outc, (void*)&Nv};
        hipError_t lerr = hipLaunchCooperativeKernel((const void*)k_hops_fused,
                                                     gF, blk, args, 0, stream);
        if (lerr != hipSuccess) coop_ok = false;
    }
    if (!coop_ok) {
        dim3 gHop(((size_t)N * 4 + B - 1) / B);
        k_hop_gather<<<gHop, blk, 0, stream>>>(rp2, col, dinv, (const h8*)hA,
                                               (h8*)hB, N);
        k_hop_gather<<<gHop, blk, 0, stream>>>(rp2, col, dinv, (const h8*)hB,
                                               (h8*)hA, N);
        k_hop3_linear<<<gF, blk, 0, stream>>>(rp2, col, dinv, (const h8*)hA,
                                              W, b, out, N);
    }
}

// Round 7
// 198.988 us; speedup vs baseline: 1.0683x; 1.0071x over previous
//
#include <hip/hip_runtime.h>

// SGConv: K=3 hops of \hat{A} x (symmetric gcn_norm w/ self-loops), then Linear.
// N=100000, E=1600000, F_in=32, F_out=64.
// Round 23 (FINAL): exact R17 configuration (measured 200.3/200.6/200.4us),
// coop-fusion path removed (R22: real coop execution = 448us, 3.3x slower;
// grid.sync serializes hops to straggler-max and kills inter-launch overlap).
//
// Bottleneck model (established R15-R22): hop gather is bound by the
// scattered 64B line-request service rate, already saturated at the
// structural minimum of 1 request/edge (fp16 64B rows; 4x16B lanes
// coalesce to one line request). Time moved ONLY when touch count moved
// (R18 2x touches -> +12.7%); MLP depth (R15/R17), col latency pipelining
// (R19), nt-hint polarity (R15/R19), L2-fill locality (R20: FETCH -35% at
// identical time), and launch-boundary fusion (R22) were all neutral or
// negative. Floor: 3 x 1.7M requests ~ 136us + ~25us streaming build +
// fused linear ~ 200us. fp8 rows (32B) excluded by absmax budget.
//
// Structure: two-level radix partition (13 supers -> 32 subs each),
// per-wave replicated bin counters, per-sub counting sort + fused
// dinv-prescale to fp16, two ping-pong gather hops (4 lanes/node, 16B
// loads, unroll-4), final hop fused with Linear via conflict-free LDS
// epilogue (W rows in registers, broadcast hl reads).

#define F_IN 32
#define F_OUT 64
#define SB_SHIFT 13                  // 8192 nodes per super-bucket
#define NSB_MAX 16
#define SUB_SHIFT 8                  // 256 nodes per sub-bucket
#define SUB (1 << SUB_SHIFT)
#define SPS 32                       // subs per super (8192/256)
#define EPB1 2048
#define EPB2 4096
#define SCAP 147456                  // super slab cap (mean 131072, sd ~347)
#define SUBCAP 6144                  // sub slab cap (mean 4096, sd ~64)
#define BPS (SCAP / EPB2)            // 36 blocks per super in k_bin2

typedef float f4 __attribute__((ext_vector_type(4)));
typedef float f8 __attribute__((ext_vector_type(8)));
typedef _Float16 h8 __attribute__((ext_vector_type(8)));   // 16B
typedef int i2 __attribute__((ext_vector_type(2)));

// ---------- Level-1 bin: 13 supers; per-wave replicated hist/cursors ----------
__global__ __launch_bounds__(256) void k_bin1(const int* __restrict__ ei,
                                              int* __restrict__ scur,
                                              unsigned* __restrict__ b1, int E) {
    __shared__ unsigned stage[EPB1];          // 8 KB
    __shared__ unsigned char bidl[EPB1];      // 2 KB
    __shared__ int h4w[4][NSB_MAX];           // per-wave hist
    __shared__ int f4w[4][NSB_MAX];           // per-wave cursors
    __shared__ int lscanx[NSB_MAX], lbase[NSB_MAX];
    unsigned rec[EPB1 / 256];
    int      bk[EPB1 / 256];
    int tid = threadIdx.x;
    int wv = tid >> 6;
    int base = blockIdx.x * EPB1;
    int cnt = E - base; if (cnt > EPB1) cnt = EPB1;

    if (tid < 64) { h4w[tid >> 4][tid & 15] = 0; }
    __syncthreads();
#pragma unroll
    for (int k = 0; k < EPB1 / 256; ++k) {
        int i = base + k * 256 + tid;
        bk[k] = -1;
        if (i < E) {
            unsigned s = (unsigned)ei[i];
            unsigned d = (unsigned)ei[E + i];
            int b = d >> SB_SHIFT;
            rec[k] = (s << SB_SHIFT) | (d & ((1u << SB_SHIFT) - 1));
            bk[k] = b;
            atomicAdd(&h4w[wv][b], 1);
        }
    }
    __syncthreads();
    if (tid < 16) {
        int t0 = h4w[0][tid], t1 = h4w[1][tid], t2 = h4w[2][tid], t3 = h4w[3][tid];
        int tot = t0 + t1 + t2 + t3;
        int inc = tot;
#pragma unroll
        for (int off = 1; off < 16; off <<= 1) {
            int t = __shfl_up(inc, off);
            if (tid >= off) inc += t;
        }
        int excl = inc - tot;
        lscanx[tid] = excl;
        lbase[tid] = tot ? atomicAdd(&scur[tid], tot) : 0;
        f4w[0][tid] = excl;
        f4w[1][tid] = excl + t0;
        f4w[2][tid] = excl + t0 + t1;
        f4w[3][tid] = excl + t0 + t1 + t2;
    }
    __syncthreads();
#pragma unroll
    for (int k = 0; k < EPB1 / 256; ++k) {
        if (bk[k] >= 0) {
            int loc = atomicAdd(&f4w[wv][bk[k]], 1);
            stage[loc] = rec[k];
            bidl[loc] = (unsigned char)bk[k];
        }
    }
    __syncthreads();
    for (int k = 0; k < EPB1 / 256; ++k) {
        int idx = k * 256 + tid;
        if (idx < cnt) {
            int b = bidl[idx];
            b1[(size_t)b * SCAP + lbase[b] + (idx - lscanx[b])] = stage[idx];
        }
    }
}

// ---------- Level-2 bin: 32 subs per super; per-wave replicated ----------
__global__ __launch_bounds__(256) void k_bin2(const unsigned* __restrict__ b1,
                                              const int* __restrict__ scur,
                                              int* __restrict__ subcur,
                                              unsigned* __restrict__ b2) {
    int sb = blockIdx.x / BPS;
    int base = (blockIdx.x % BPS) * EPB2;
    int count = scur[sb];
    if (base >= count) return;
    int cnt = count - base; if (cnt > EPB2) cnt = EPB2;
    const unsigned* src = b1 + (size_t)sb * SCAP + base;

    __shared__ unsigned stage[EPB2];          // 16 KB
    __shared__ unsigned char bidl[EPB2];      // 4 KB
    __shared__ int h4w[4][SPS];
    __shared__ int f4w[4][SPS];
    __shared__ int lscanx[SPS], lbase[SPS];
    unsigned rec[EPB2 / 256];
    int tid = threadIdx.x;
    int wv = tid >> 6;
    if (tid < 128) h4w[tid >> 5][tid & 31] = 0;
    __syncthreads();
#pragma unroll
    for (int k = 0; k < EPB2 / 256; ++k) {
        int i = k * 256 + tid;
        rec[k] = 0xFFFFFFFFu;
        if (i < cnt) {
            unsigned r = src[i];
            rec[k] = r;
            atomicAdd(&h4w[wv][(r >> SUB_SHIFT) & (SPS - 1)], 1);
        }
    }
    __syncthreads();
    if (tid < 32) {
        int t0 = h4w[0][tid], t1 = h4w[1][tid], t2 = h4w[2][tid], t3 = h4w[3][tid];
        int tot = t0 + t1 + t2 + t3;
        int inc = tot;
#pragma unroll
        for (int off = 1; off < 32; off <<= 1) {
            int t = __shfl_up(inc, off);
            if (tid >= off) inc += t;
        }
        int excl = inc - tot;
        lscanx[tid] = excl;
        lbase[tid] = tot ? atomicAdd(&subcur[sb * SPS + tid], tot) : 0;
        f4w[0][tid] = excl;
        f4w[1][tid] = excl + t0;
        f4w[2][tid] = excl + t0 + t1;
        f4w[3][tid] = excl + t0 + t1 + t2;
    }
    __syncthreads();
#pragma unroll
    for (int k = 0; k < EPB2 / 256; ++k) {
        if (rec[k] != 0xFFFFFFFFu) {
            int b = (rec[k] >> SUB_SHIFT) & (SPS - 1);
            int loc = atomicAdd(&f4w[wv][b], 1);
            stage[loc] = rec[k];
            bidl[loc] = (unsigned char)b;
        }
    }
    __syncthreads();
    for (int k = 0; k < EPB2 / 256; ++k) {
        int idx = k * 256 + tid;
        if (idx < cnt) {
            unsigned r = stage[idx];
            int b = bidl[idx];
            unsigned packed = ((r >> SB_SHIFT) << SUB_SHIFT) | (r & (SUB - 1));
            b2[(size_t)(sb * SPS + b) * SUBCAP + lbase[b] + (idx - lscanx[b])] = packed;
        }
    }
}

// ---------- fill3: one 256-thr block per 256-node sub + fused prescale ----------
__global__ __launch_bounds__(256) void k_fill3(const unsigned* __restrict__ b2,
                                               const int* __restrict__ subcur,
                                               const f4* __restrict__ x,
                                               float* __restrict__ dinv,
                                               i2* __restrict__ rp2,
                                               int* __restrict__ col,
                                               h8* __restrict__ g0, int N) {
    __shared__ unsigned stage[SUBCAP];        // 24 KB
    __shared__ int h[SUB];
    __shared__ float dl[SUB];
    __shared__ int wsum[4];
    int tid = threadIdx.x;
    int g = blockIdx.x;
    int count = subcur[g];
    int sbase = g * SUBCAP;
    int n0 = g << SUB_SHIFT;

    h[tid] = 0;
    for (int e = tid; e < count; e += 256) stage[e] = b2[(size_t)sbase + e];
    __syncthreads();
    for (int e = tid; e < count; e += 256) atomicAdd(&h[stage[e] & (SUB - 1)], 1);
    __syncthreads();

    int deg = h[tid];
    int lane = tid & 63, wid = tid >> 6;
    int inc = deg;
#pragma unroll
    for (int off = 1; off < 64; off <<= 1) {
        int t = __shfl_up(inc, off);
        if (lane >= off) inc += t;
    }
    if (lane == 63) wsum[wid] = inc;
    __syncthreads();
    if (wid == 0) {
        int v = (lane < 4) ? wsum[lane] : 0;
#pragma unroll
        for (int off = 1; off < 4; off <<= 1) {
            int t = __shfl_up(v, off);
            if (lane >= off) v += t;
        }
        if (lane < 4) wsum[lane] = v;
    }
    __syncthreads();
    int incl = inc + (wid ? wsum[wid - 1] : 0);
    int excl = incl - deg;

    int node = n0 + tid;
    float di = rsqrtf(1.0f + (float)deg);
    dl[tid] = di;
    if (node < N) {
        dinv[node] = di;
        rp2[node] = (i2){sbase + excl, sbase + incl};
    }
    h[tid] = excl;
    __syncthreads();

    for (int e = tid; e < count; e += 256) {
        unsigned r = stage[e];
        int slot = sbase + atomicAdd(&h[r & (SUB - 1)], 1);
        col[slot] = (int)(r >> SUB_SHIFT);
    }

    // fused prescale for this block's nodes: g0 = fp16(dinv .* x), 16B stores
    for (int idx = tid; idx < SUB * 4; idx += 256) {
        int nl = idx >> 2;
        int q = idx & 3;
        int node2 = n0 + nl;
        if (node2 < N) {
            int gi = node2 * 8 + q * 2;
            f4 vlo = dl[nl] * x[gi];
            f4 vhi = dl[nl] * x[gi + 1];
            f8 v = __builtin_shufflevector(vlo, vhi, 0, 1, 2, 3, 4, 5, 6, 7);
            g0[(size_t)node2 * 4 + q] = __builtin_convertvector(v, h8);
        }
    }
}

// ---------- shared gather core: self-loop + unroll-4 neighbor sum ----------
__device__ __forceinline__ f8 gather_row(const h8* __restrict__ gin,
                                         int e0, int e1, const int* __restrict__ col,
                                         int n, int q) {
    f8 a0 = __builtin_convertvector(gin[(size_t)n * 4 + q], f8);  // self-loop
    f8 a1 = {0.f, 0.f, 0.f, 0.f, 0.f, 0.f, 0.f, 0.f};
    int e = e0;
    for (; e + 3 < e1; e += 4) {
        int s0 = col[e], s1 = col[e + 1], s2 = col[e + 2], s3 = col[e + 3];
        h8 h0 = gin[(size_t)s0 * 4 + q];
        h8 h1 = gin[(size_t)s1 * 4 + q];
        h8 h2 = gin[(size_t)s2 * 4 + q];
        h8 h3 = gin[(size_t)s3 * 4 + q];
        a0 += __builtin_convertvector(h0, f8);
        a1 += __builtin_convertvector(h1, f8);
        a0 += __builtin_convertvector(h2, f8);
        a1 += __builtin_convertvector(h3, f8);
    }
    for (; e < e1; ++e) a0 += __builtin_convertvector(gin[(size_t)col[e] * 4 + q], f8);
    return a0 + a1;
}

// ---------- Mid hop (hops 1,2): 4 lanes/row, 16B loads, unroll-4 ----------
__global__ __launch_bounds__(256) void k_hop_gather(const i2* __restrict__ rp2,
                                                    const int* __restrict__ col,
                                                    const float* __restrict__ dinv,
                                                    const h8* __restrict__ gin,
                                                    h8* __restrict__ gout, int N) {
    int t = blockIdx.x * blockDim.x + threadIdx.x;
    int n = t >> 2;
    if (n >= N) return;
    int q = t & 3;
    i2 r2 = rp2[n];
    f8 acc = gather_row(gin, r2.x, r2.y, col, n, q);
    float di = dinv[n];
    gout[(size_t)n * 4 + q] = __builtin_convertvector((di * di) * acc, h8);
}

// ---------- Final hop FUSED with linear; conflict-free epilogue ----------
// Block = 256 thr = 64 nodes x 4 lanes (gather), then 16 passes of 4 nodes x 64 o.
__global__ __launch_bounds__(256) void k_hop3_linear(const i2* __restrict__ rp2,
                                                     const int* __restrict__ col,
                                                     const float* __restrict__ dinv,
                                                     const h8* __restrict__ gin,
                                                     const float* __restrict__ W,
                                                     const float* __restrict__ bias,
                                                     float* __restrict__ out, int N) {
    __shared__ float Wl[F_OUT][F_IN + 1];   // 8.4 KB
    __shared__ float hl[64][F_IN + 1];      // 8.4 KB
    int tid = threadIdx.x;
    for (int idx = tid; idx < F_OUT * F_IN; idx += 256)
        Wl[idx >> 5][idx & 31] = W[idx];

    int nl = tid >> 2;                 // 0..31 -> 0..63 local node
    int q = tid & 3;
    int nbase = blockIdx.x * 64;
    int n = nbase + nl;
    if (n < N) {
        i2 r2 = rp2[n];
        f8 acc = gather_row(gin, r2.x, r2.y, col, n, q);
        f8 r = dinv[n] * acc;
#pragma unroll
        for (int i = 0; i < 8; ++i) hl[nl][q * 8 + i] = r[i];
    }
    __syncthreads();
    // W row -> registers, conflict-free: lanes o=0..63 read Wl[o][f], bank (o+f)%32
    int o = tid & 63;
    float wreg[F_IN];
#pragma unroll
    for (int f = 0; f < F_IN; ++f) wreg[f] = Wl[o][f];
    float bv = bias[o];
    // 16 passes x 4 nodes: node index wave-uniform -> hl reads broadcast
    int nchunk = tid >> 6;  // 0..3
#pragma unroll
    for (int p = 0; p < 16; ++p) {
        int nloc = p * 4 + nchunk;
        int nn = nbase + nloc;
        if (nn < N) {
            float acc = bv;
#pragma unroll
            for (int f = 0; f < F_IN; ++f) acc += hl[nloc][f] * wreg[f];
            out[(size_t)nn * F_OUT + o] = acc;
        }
    }
}

extern "C" void kernel_launch(void* const* d_in, const int* in_sizes, int n_in,
                              void* d_out, int out_size, void* d_ws, size_t ws_size,
                              hipStream_t stream) {
    const float* x  = (const float*)d_in[0];
    const int*   ei = (const int*)d_in[1];   // [2,E] int32: src row then dst row
    const float* W  = (const float*)d_in[2];
    const float* b  = (const float*)d_in[3];
    float* out = (float*)d_out;

    const int N = in_sizes[0] / F_IN;
    const int E = in_sizes[1] / 2;
    const int NSB  = (N + (1 << SB_SHIFT) - 1) >> SB_SHIFT;   // 13
    const int NSUB = (N + SUB - 1) >> SUB_SHIFT;              // 391

    // ws: scur(16) | subcur(16*32) | rp2(2N) | dinv(N) | b1 | b2 | col | hA hB
    int* scur   = (int*)d_ws;
    int* subcur = scur + NSB_MAX;
    i2*  rp2    = (i2*)(subcur + NSB_MAX * SPS);
    float* dinv = (float*)(rp2 + N);
    unsigned* b1 = (unsigned*)(((uintptr_t)(dinv + N) + 255) & ~(uintptr_t)255);
    unsigned* b2 = b1 + (size_t)NSB_MAX * SCAP;
    int* col     = (int*)(b2 + (size_t)NSB_MAX * SPS * SUBCAP);
    _Float16* hA = (_Float16*)(((uintptr_t)(col + (size_t)NSB_MAX * SPS * SUBCAP) + 255)
                               & ~(uintptr_t)255);
    _Float16* hB = hA + (size_t)N * F_IN;

    const int B = 256;
    dim3 blk(B);

    hipMemsetAsync(scur, 0, (NSB_MAX + NSB_MAX * SPS) * sizeof(int), stream);

    // two-level radix partition
    k_bin1<<<dim3((E + EPB1 - 1) / EPB1), blk, 0, stream>>>(ei, scur, b1, E);
    k_bin2<<<dim3(NSB * BPS), blk, 0, stream>>>(b1, scur, subcur, b2);

    // per-sub counting sort + fused prescale (g0 -> hA)
    k_fill3<<<dim3(NSUB), blk, 0, stream>>>(b2, subcur, (const f4*)x,
                                            dinv, rp2, col, (h8*)hA, N);

    // hops 1,2 (ping-pong): hA -> hB -> hA
    dim3 gHop(((size_t)N * 4 + B - 1) / B);
    k_hop_gather<<<gHop, blk, 0, stream>>>(rp2, col, dinv, (const h8*)hA, (h8*)hB, N);
    k_hop_gather<<<gHop, blk, 0, stream>>>(rp2, col, dinv, (const h8*)hB, (h8*)hA, N);

    // hop 3 fused with linear: hA -> out
    k_hop3_linear<<<dim3((N + 63) / 64), blk, 0, stream>>>(rp2, col, dinv,
                                                           (const h8*)hA, W, b, out, N);
}